// Round 4
// baseline (100.234 us; speedup 1.0000x reference)
//
#include <hip/hip_runtime.h>

typedef _Float16 f16;
typedef _Float16 f16x8 __attribute__((ext_vector_type(8)));
typedef _Float16 f16x4 __attribute__((ext_vector_type(4)));
typedef float f32x4 __attribute__((ext_vector_type(4)));

#define MFMA16(a,b,c) __builtin_amdgcn_mfma_f32_16x16x32_f16((a),(b),(c),0,0,0)

__device__ __forceinline__ float sigm(float x){ return 1.0f/(1.0f+__expf(-x)); }
__device__ __forceinline__ float tanhf_(float x){ return 1.0f - 2.0f/(1.0f+__expf(2.0f*x)); }

// One block (256 thr, 4 waves) per batch element; 2 blocks/CU.
// Algebra: Y = node@(W1@W2) + b1@W2 ;  Z(=h2) = A@Y + Y + b2 ;  hb = A@Z + Z.
// fp16 MFMA on centered quantities (Ac = A-2, d2 = Z - mean_n Z); all rank-1 /
// mean parts carried exactly in fp32 (sumY, c, rowsum(A), c@Ws).
#define S128 136
#define S68  68
#define S72  72

// LDS map (bytes):
// 0     Alds[128][136]f16 =34816 ; resid[128][72]f16=18432 overlays at 0 after M2
// 34816 R1: stg[5120]f32 (20480, spans into R2) -> YB[64][136]f16 -> WsB[128][68]f16
// 52224 R2: nodeT[5][128]f32 (2560, transient)  -> d2B[64][136]f16 -> WtB[128][68]f16
// 69632 node_l[640]f32 (t1l/t2l overlay after G4)
// 72192 Wsnd[640]f32 | 74752 Wtnd[640]f32
// 77312 W12s[6][64]f32 1536 -> g_ac[128]f32 overlays (W12s dead after Y-init)
// 78848 b2L[64] | 79104 sumY[64] | 79360 rsL[128] | 79872 c_ac[64]
// 80128 cw[128] | 80640 ctw[128]  -> total 81152 (rounds to 81408; 2/CU fits)

__global__ __launch_bounds__(256,2) void k_main(
    const float* __restrict__ adj,
    const float* __restrict__ node_g,
    const float* __restrict__ W1,  const float* __restrict__ b1,
    const float* __restrict__ W2,  const float* __restrict__ b2,
    const float* __restrict__ Ws,  const float* __restrict__ bs,
    const float* __restrict__ Wt,  const float* __restrict__ bt,
    const float* __restrict__ Wl1, const float* __restrict__ bl1,
    const float* __restrict__ Wl2, const float* __restrict__ bl2,
    const float* __restrict__ Wo,  const float* __restrict__ bo,
    float* __restrict__ out)
{
    __shared__ __align__(16) char smem[81152];
    f16*   Alds  = (f16*)(smem);
    f16*   resid = (f16*)(smem);
    float* stg   = (float*)(smem+34816);
    f16*   YB    = (f16*)(smem+34816);
    f16*   WsB   = (f16*)(smem+34816);
    float* nodeT = (float*)(smem+52224);
    f16*   d2B   = (f16*)(smem+52224);
    f16*   WtB   = (f16*)(smem+52224);
    float* node_l= (float*)(smem+69632);
    float* t1l   = (float*)(smem+69632);
    float* t2l   = (float*)(smem+70144);
    float* Wsnd  = (float*)(smem+72192);
    float* Wtnd  = (float*)(smem+74752);
    float* W12s  = (float*)(smem+77312);
    float* g_ac  = (float*)(smem+77312);   // overlays W12s (dead after Y-init)
    float* b2L   = (float*)(smem+78848);
    float* sumY  = (float*)(smem+79104);
    float* rsL   = (float*)(smem+79360);
    float* c_ac  = (float*)(smem+79872);
    float* cw    = (float*)(smem+80128);
    float* ctw   = (float*)(smem+80640);

    const int bidx = blockIdx.x;
    const int tid  = threadIdx.x;
    const int w    = tid>>6, lane = tid&63;
    const int l15  = lane&15, l4 = lane>>4;

    // ---- phase 0: zero accumulators + stage small fp32 arrays ----
    if (tid<64){ sumY[tid]=0.f; c_ac[tid]=0.f; b2L[tid]=b2[tid]; }
    for (int i=tid;i<640;i+=256){
        node_l[i] = node_g[bidx*640+i];
        Wsnd[i]   = Ws[8192+i];
        Wtnd[i]   = Wt[8192+i];
    }

    // ---- issue first adj prefetch, compute W12 = [W1;b1]@W2 under its latency ----
    const float4* asrc = (const float4*)(adj + (long long)bidx*81920);
    float4 pre[5];
    #pragma unroll
    for (int k=0;k<5;++k) pre[k] = asrc[k*256+tid];

    for (int idx=tid; idx<384; idx+=256){
        int m = idx>>6, k = idx&63;
        float s = 0.f;
        if (m<5){ for (int c=0;c<128;++c) s += W1[m*128+c]*W2[c*64+k]; }
        else    { for (int c=0;c<128;++c) s += b1[c]*W2[c*64+k]; }
        W12s[idx] = s;
    }
    { // write chunk 0
        float4* dst = (float4*)stg;
        #pragma unroll
        for (int k=0;k<5;++k) dst[k*256+tid] = pre[k];
    }
    __syncthreads();

    // ---- stream adj: 16 chunks x 8 rows; reg-prefetch next chunk ----
    for (int c=0; c<16; ++c){
        if (c+1<16){
            #pragma unroll
            for (int k=0;k<5;++k) pre[k] = asrc[(c+1)*1280 + k*256 + tid];
        }
        float4 v0 = *(const float4*)&stg[20*tid];
        float4 v1 = *(const float4*)&stg[20*tid+4];
        float4 v2 = *(const float4*)&stg[20*tid+8];
        float4 v3 = *(const float4*)&stg[20*tid+12];
        float4 v4 = *(const float4*)&stg[20*tid+16];
        float s0 = v0.y + v0.z + v0.w + v1.x;
        float s1 = v1.z + v1.w + v2.x + v2.y;
        float s2 = v2.w + v3.x + v3.y + v3.z;
        float s3 = v4.x + v4.y + v4.z + v4.w;
        int r  = c*8 + (tid>>5);
        int j0 = (tid&31)*4;
        f16x4 o; o[0]=(f16)(s0-2.0f); o[1]=(f16)(s1-2.0f);
                 o[2]=(f16)(s2-2.0f); o[3]=(f16)(s3-2.0f);
        *(f16x4*)&Alds[r*S128 + j0] = o;
        float v = s0+s1+s2+s3;     // exact fp32 rowsum (32 lanes per row)
        v += __shfl_xor(v, 1, 64); v += __shfl_xor(v, 2, 64);
        v += __shfl_xor(v, 4, 64); v += __shfl_xor(v, 8, 64);
        v += __shfl_xor(v,16, 64);
        if ((tid&31)==0) rsL[r] = v;
        __syncthreads();           // all stg reads done
        if (c+1<16){
            float4* dst = (float4*)stg;
            #pragma unroll
            for (int k=0;k<5;++k) dst[k*256+tid] = pre[k];
        }
        __syncthreads();           // stg ready
    }

    // ---- nodeT transpose (transient, in R2) ----
    for (int i=tid;i<640;i+=256){
        int n = i/5, m = i-5*n;
        nodeT[m*128+n] = node_l[i];
    }
    __syncthreads();

    // ---- Y = node@W12 + b12, fp32 -> f16 into YB [k][n]; exact f16 colsums ----
    {
        int k = tid&63, n0 = (tid>>6)*32;
        float w12v[5];
        #pragma unroll
        for (int m=0;m<5;++m) w12v[m] = W12s[m*64+k];
        float bv = W12s[320+k];
        float sy = 0.f;
        for (int g=0; g<8; ++g){
            int n = n0 + g*4;
            f32x4 x0 = *(const f32x4*)&nodeT[n];
            f32x4 x1 = *(const f32x4*)&nodeT[128+n];
            f32x4 x2 = *(const f32x4*)&nodeT[256+n];
            f32x4 x3 = *(const f32x4*)&nodeT[384+n];
            f32x4 x4 = *(const f32x4*)&nodeT[512+n];
            f16x4 pk;
            #pragma unroll
            for (int r=0;r<4;++r){
                float y = bv + x0[r]*w12v[0] + x1[r]*w12v[1] + x2[r]*w12v[2]
                             + x3[r]*w12v[3] + x4[r]*w12v[4];
                f16 yh = (f16)y;
                pk[r] = yh;
                sy += (float)yh;
            }
            *(f16x4*)&YB[k*S128+n] = pk;
        }
        atomicAdd(&sumY[k], sy);
    }
    if (tid<128) g_ac[tid]=0.f;    // g_ac overlays W12s; W12s still read above ->
    __syncthreads();               // (safe: only threads' own W12s reads precede; barrier)

    // ---- M1: Z = Ac@Y + 2*sumY + Yf16 + b2  (2 row-passes x 4 col-tiles) ----
    f32x4 accZ[2][4];
    #pragma unroll
    for (int p=0;p<2;++p){
        const int rbp = (2*w+p)*16 + l4*4;
        const int irp = (2*w+p)*16 + l15;
        #pragma unroll
        for (int ct=0;ct<4;++ct){
            int k = ct*16+l15;
            float base = 2.0f*sumY[k] + b2L[k];
            f16x4 y4 = *(const f16x4*)&YB[k*S128 + rbp];
            #pragma unroll
            for (int r=0;r<4;++r) accZ[p][ct][r] = base + (float)y4[r];
        }
        #pragma unroll
        for (int kk=0;kk<4;++kk){
            int ko = kk*32 + l4*8;
            f16x8 af = *(const f16x8*)&Alds[irp*S128 + ko];
            #pragma unroll
            for (int ct=0;ct<4;++ct){
                f16x8 bf = *(const f16x8*)&YB[(ct*16+l15)*S128 + ko];
                accZ[p][ct] = MFMA16(af, bf, accZ[p][ct]);
            }
        }
        #pragma unroll
        for (int ct=0;ct<4;++ct){  // column sums for mean c
            float v = accZ[p][ct][0]+accZ[p][ct][1]+accZ[p][ct][2]+accZ[p][ct][3];
            v += __shfl_xor(v,16,64); v += __shfl_xor(v,32,64);
            if (lane<16) atomicAdd(&c_ac[ct*16+lane], v);
        }
    }
    __syncthreads();
    if (tid<64) c_ac[tid] *= (1.0f/128.0f);
    __syncthreads();

    // ---- d2 = Z - c  (B-layout [n2][j]); stage WsB (over YB); cw/ctw fp32 ----
    #pragma unroll
    for (int p=0;p<2;++p){
        const int rbp = (2*w+p)*16 + l4*4;
        #pragma unroll
        for (int ct=0;ct<4;++ct){
            int n2 = ct*16+l15; float cv = c_ac[n2];
            f16x4 pk;
            #pragma unroll
            for (int r=0;r<4;++r) pk[r] = (f16)(accZ[p][ct][r]-cv);
            *(f16x4*)&d2B[n2*S128 + rbp] = pk;
        }
    }
    for (int idx=tid; idx<8192; idx+=256){
        int n2 = idx>>7, aux = idx&127;
        WsB[aux*S68+n2] = (f16)Ws[idx];
    }
    {
        int aux = tid&127;
        const float* Wx = (tid<128)? Ws : Wt;
        float s=0.f;
        for (int n2=0;n2<64;++n2) s += c_ac[n2]*Wx[n2*128+aux];
        ((tid<128)? cw : ctw)[aux] = s;
    }
    __syncthreads();

    // ---- M2: acc3 = Ac@d2 + d2 ----
    f32x4 acc3[2][4];
    #pragma unroll
    for (int p=0;p<2;++p){
        const int rbp = (2*w+p)*16 + l4*4;
        const int irp = (2*w+p)*16 + l15;
        #pragma unroll
        for (int ct=0;ct<4;++ct){
            int n2 = ct*16+l15;
            f16x4 d4 = *(const f16x4*)&d2B[n2*S128 + rbp];
            #pragma unroll
            for (int r=0;r<4;++r) acc3[p][ct][r] = (float)d4[r];
        }
        #pragma unroll
        for (int kk=0;kk<4;++kk){
            int ko = kk*32 + l4*8;
            f16x8 af = *(const f16x8*)&Alds[irp*S128 + ko];
            #pragma unroll
            for (int ct=0;ct<4;++ct){
                f16x8 bf = *(const f16x8*)&d2B[(ct*16+l15)*S128 + ko];
                acc3[p][ct] = MFMA16(af, bf, acc3[p][ct]);
            }
        }
    }
    __syncthreads();   // Alds & d2B now dead

    // ---- resid (overlays Alds) + WtB stage (overlays d2B) ----
    #pragma unroll
    for (int p=0;p<2;++p){
        const int rbp = (2*w+p)*16 + l4*4;
        #pragma unroll
        for (int ct=0;ct<4;++ct){
            int n2 = ct*16+l15;
            #pragma unroll
            for (int r=0;r<4;++r) resid[(rbp+r)*S72 + n2] = (f16)acc3[p][ct][r];
        }
    }
    for (int idx=tid; idx<8192; idx+=256){
        int n2 = idx>>7, aux = idx&127;
        WtB[aux*S68+n2] = (f16)Wt[idx];
    }
    __syncthreads();

    // ---- G4: S/T = resid@Ws/Wt + (rs+1)*cw/ctw + node-part + bias; gated sum ----
    #pragma unroll
    for (int p=0;p<2;++p){
        const int rbp = (2*w+p)*16 + l4*4;
        const int irp = (2*w+p)*16 + l15;
        float nodev[4][5]; float rs1[4];
        #pragma unroll
        for (int r=0;r<4;++r){
            rs1[r] = rsL[rbp+r] + 1.0f;
            #pragma unroll
            for (int m=0;m<5;++m) nodev[r][m] = node_l[(rbp+r)*5+m];
        }
        f32x4 aS[8], aT[8];
        #pragma unroll
        for (int ct=0;ct<8;++ct){
            int aux = ct*16+l15;
            float cwv = cw[aux], ctv = ctw[aux];
            float bsv = bs[aux], btv = bt[aux];
            #pragma unroll
            for (int r=0;r<4;++r){
                float ns=0.f, nt=0.f;
                #pragma unroll
                for (int m=0;m<5;++m){
                    float nv = nodev[r][m];
                    ns += nv*Wsnd[m*128+aux];
                    nt += nv*Wtnd[m*128+aux];
                }
                aS[ct][r] = bsv + rs1[r]*cwv + ns;
                aT[ct][r] = btv + rs1[r]*ctv + nt;
            }
        }
        #pragma unroll
        for (int kk=0;kk<2;++kk){
            int ko = kk*32 + l4*8;
            f16x8 af = *(const f16x8*)&resid[irp*S72 + ko];
            #pragma unroll
            for (int ct=0;ct<8;++ct){
                f16x8 bsf = *(const f16x8*)&WsB[(ct*16+l15)*S68 + ko];
                aS[ct] = MFMA16(af, bsf, aS[ct]);
                f16x8 btf = *(const f16x8*)&WtB[(ct*16+l15)*S68 + ko];
                aT[ct] = MFMA16(af, btf, aT[ct]);
            }
        }
        #pragma unroll
        for (int ct=0;ct<8;++ct){
            float v = 0.f;
            #pragma unroll
            for (int r=0;r<4;++r) v += sigm(aS[ct][r])*tanhf_(aT[ct][r]);
            v += __shfl_xor(v,16,64); v += __shfl_xor(v,32,64);
            if (lane<16) atomicAdd(&g_ac[ct*16+lane], v);
        }
    }
    __syncthreads();

    // ---- head (t1l/t2l overlay node_l, now dead) ----
    if (tid<128) g_ac[tid] = tanhf_(g_ac[tid]);
    __syncthreads();
    if (tid<128){
        float s = bl1[tid];
        for (int a2=0;a2<128;++a2) s += g_ac[a2]*Wl1[a2*128+tid];
        t1l[tid] = s;
    }
    __syncthreads();
    if (tid<64){
        float s = bl2[tid];
        for (int o=0;o<128;++o) s += t1l[o]*Wl2[o*64+tid];
        t2l[tid] = s;
        out[512 + bidx*64 + tid] = s;   // output 1: g [B,64]
    }
    __syncthreads();
    if (w==0){
        float v = t2l[lane]*Wo[lane];
        v += __shfl_xor(v,1,64);  v += __shfl_xor(v,2,64);
        v += __shfl_xor(v,4,64);  v += __shfl_xor(v,8,64);
        v += __shfl_xor(v,16,64); v += __shfl_xor(v,32,64);
        if (lane==0) out[bidx] = v + bo[0];   // output 0: out [B,1]
    }
}

extern "C" void kernel_launch(void* const* d_in, const int* in_sizes, int n_in,
                              void* d_out, int out_size, void* d_ws, size_t ws_size,
                              hipStream_t stream) {
    (void)in_sizes; (void)n_in; (void)out_size; (void)d_ws; (void)ws_size;
    const float* adj  = (const float*)d_in[0];
    const float* node = (const float*)d_in[1];
    const float* W1   = (const float*)d_in[2];
    const float* b1   = (const float*)d_in[3];
    const float* W2   = (const float*)d_in[4];
    const float* b2   = (const float*)d_in[5];
    const float* Ws   = (const float*)d_in[6];
    const float* bs   = (const float*)d_in[7];
    const float* Wt   = (const float*)d_in[8];
    const float* bt   = (const float*)d_in[9];
    const float* Wl1  = (const float*)d_in[10];
    const float* bl1  = (const float*)d_in[11];
    const float* Wl2  = (const float*)d_in[12];
    const float* bl2  = (const float*)d_in[13];
    const float* Wo   = (const float*)d_in[14];
    const float* bo   = (const float*)d_in[15];

    k_main<<<dim3(512), dim3(256), 0, stream>>>(adj, node, W1,b1,W2,b2,Ws,bs,Wt,bt,
                                                Wl1,bl1,Wl2,bl2,Wo,bo, (float*)d_out);
}

// Round 5
// 75.163 us; speedup vs baseline: 1.3336x; 1.3336x over previous
//
#include <hip/hip_runtime.h>

typedef _Float16 f16;
typedef _Float16 f16x8 __attribute__((ext_vector_type(8)));
typedef _Float16 f16x4 __attribute__((ext_vector_type(4)));
typedef float f32x4 __attribute__((ext_vector_type(4)));

#define MFMA16(a,b,c) __builtin_amdgcn_mfma_f32_16x16x32_f16((a),(b),(c),0,0,0)

__device__ __forceinline__ float sigm(float x){ return 1.0f/(1.0f+__expf(-x)); }
__device__ __forceinline__ float tanhf_(float x){ return 1.0f - 2.0f/(1.0f+__expf(2.0f*x)); }

typedef __attribute__((address_space(1))) unsigned g_u32;
typedef __attribute__((address_space(3))) unsigned l_u32;
__device__ __forceinline__ void gload16(const void* g, void* l){
    // async global->LDS DMA, 16B per lane; LDS dest = wave-uniform base + lane*16
    __builtin_amdgcn_global_load_lds((g_u32*)g, (l_u32*)l, 16, 0, 0);
}

#define S128 136
#define S68  68
#define S72  72

// One block (256 thr, 4 waves) per batch element; 2 blocks/CU (LDS = 81920 exactly).
// Algebra: Y = node@(W1@W2)+b1@W2 ; Z = A@Y + Y + b2 ; hb = A@Z + Z.
// fp16 MFMA on centered split quantities (Ac=A-2; Y,d2 as hi+lo fp16 pairs);
// rank-1 / mean parts exact fp32 (sumY, c, rowsum(A), c@Ws).
//
// LDS map (bytes):
// 0      Alds[128][136]f16 (34816) -> resid[128][72] overlays after M2
// 34816  stgA(20480) -> Yhi[64][136] -> d2lo -> WsB[128][68]
// 52224  nodeT[640]f32 (Y phase) -> Wsnd[640] (G4)
// 54784  g_ac[128]f32
// 55296  stgB(20480) -> Ylo -> d2hi -> WtB
// 72704  Wtnd[640]f32 (G4)
// 75776  node_l[640]f32 -> t1l[128]+t2l[64] at head
// 78336  W12s[384]f32 | 79872 sumY[64] | 80128 rsL[128] | 80640 c_ac[64]
// 80896  cw[128] | 81408 ctw[128]  == 81920 total

__global__ __launch_bounds__(256,2) void k_main(
    const float* __restrict__ adj,  const float* __restrict__ node_g,
    const float* __restrict__ W1,  const float* __restrict__ b1,
    const float* __restrict__ W2,  const float* __restrict__ b2,
    const float* __restrict__ Ws,  const float* __restrict__ bs,
    const float* __restrict__ Wt,  const float* __restrict__ bt,
    const float* __restrict__ Wl1, const float* __restrict__ bl1,
    const float* __restrict__ Wl2, const float* __restrict__ bl2,
    const float* __restrict__ Wo,  const float* __restrict__ bo,
    float* __restrict__ out)
{
    __shared__ __align__(16) char smem[81920];
    f16*   Alds  = (f16*)(smem);
    f16*   resid = (f16*)(smem);
    float* stgA  = (float*)(smem+34816);
    f16*   Yhi   = (f16*)(smem+34816);
    f16*   d2lo  = (f16*)(smem+34816);
    f16*   WsB   = (f16*)(smem+34816);
    float* nodeT = (float*)(smem+52224);
    float* Wsnd  = (float*)(smem+52224);
    float* g_ac  = (float*)(smem+54784);
    float* stgB  = (float*)(smem+55296);
    f16*   Ylo   = (f16*)(smem+55296);
    f16*   d2hi  = (f16*)(smem+55296);
    f16*   WtB   = (f16*)(smem+55296);
    float* Wtnd  = (float*)(smem+72704);
    float* node_l= (float*)(smem+75776);
    float* t1l   = (float*)(smem+75776);
    float* t2l   = (float*)(smem+76288);
    float* W12s  = (float*)(smem+78336);
    float* sumY  = (float*)(smem+79872);
    float* rsL   = (float*)(smem+80128);
    float* c_ac  = (float*)(smem+80640);
    float* cw    = (float*)(smem+80896);
    float* ctw   = (float*)(smem+81408);

    const int bidx = blockIdx.x;
    const int tid  = threadIdx.x;
    const int w    = tid>>6, lane = tid&63;
    const int l15  = lane&15, l4 = lane>>4;

    // ---- phase 0: zeros, node_l, W12 = [W1;b1]@W2 (fp32) ----
    if (tid<64){ sumY[tid]=0.f; c_ac[tid]=0.f; }
    for (int i=tid;i<640;i+=256) node_l[i] = node_g[bidx*640+i];
    for (int idx=tid; idx<384; idx+=256){
        int m = idx>>6, k = idx&63;
        float s = 0.f;
        if (m<5){ for (int c=0;c<128;++c) s += W1[m*128+c]*W2[c*64+k]; }
        else    { for (int c=0;c<128;++c) s += b1[c]*W2[c*64+k]; }
        W12s[idx] = s;
    }
    __syncthreads();

    // ---- stream adj via async DMA: 16 chunks x 8 rows, counted vmcnt + raw barriers ----
    const float4* asrc = (const float4*)(adj + (long long)bidx*81920);
    float4* sA4 = (float4*)stgA;
    float4* sB4 = (float4*)stgB;
    #pragma unroll
    for (int k=0;k<5;++k) gload16(asrc +        k*256 + tid, sA4 + k*256 + (w<<6));
    #pragma unroll
    for (int k=0;k<5;++k) gload16(asrc + 1280 + k*256 + tid, sB4 + k*256 + (w<<6));

    for (int c=0;c<16;++c){
        if (c<15){ asm volatile("s_waitcnt vmcnt(5)" ::: "memory"); }   // chunk c landed; c+1 in flight
        else     { asm volatile("s_waitcnt vmcnt(0)" ::: "memory"); }
        __builtin_amdgcn_sched_barrier(0);
        __builtin_amdgcn_s_barrier();          // raw: no vmcnt drain
        const float* sb = (c&1)? stgB : stgA;
        float4 v0 = *(const float4*)&sb[20*tid];
        float4 v1 = *(const float4*)&sb[20*tid+4];
        float4 v2 = *(const float4*)&sb[20*tid+8];
        float4 v3 = *(const float4*)&sb[20*tid+12];
        float4 v4 = *(const float4*)&sb[20*tid+16];
        float s0 = v0.y + v0.z + v0.w + v1.x;
        float s1 = v1.z + v1.w + v2.x + v2.y;
        float s2 = v2.w + v3.x + v3.y + v3.z;
        float s3 = v4.x + v4.y + v4.z + v4.w;
        int r  = c*8 + (tid>>5);
        int j0 = (tid&31)*4;
        f16x4 o; o[0]=(f16)(s0-2.0f); o[1]=(f16)(s1-2.0f);
                 o[2]=(f16)(s2-2.0f); o[3]=(f16)(s3-2.0f);
        *(f16x4*)&Alds[r*S128 + j0] = o;
        float v = s0+s1+s2+s3;                 // exact fp32 rowsum (32 lanes/row)
        v += __shfl_xor(v, 1, 64); v += __shfl_xor(v, 2, 64);
        v += __shfl_xor(v, 4, 64); v += __shfl_xor(v, 8, 64);
        v += __shfl_xor(v,16, 64);
        if ((tid&31)==0) rsL[r] = v;
        __builtin_amdgcn_s_barrier();          // all waves done reading buf[c&1]
        if (c+2<16){
            float4* dst4 = (c&1)? sB4 : sA4;   // chunk c+2 reuses buf[c&1]
            #pragma unroll
            for (int k=0;k<5;++k) gload16(asrc + (c+2)*1280 + k*256 + tid, dst4 + k*256 + (w<<6));
        }
    }
    __syncthreads();

    // ---- nodeT transpose + zero g_ac ----
    for (int i=tid;i<640;i+=256){
        int n = i/5, m = i-5*n;
        nodeT[m*128+n] = node_l[i];
    }
    if (tid<128) g_ac[tid]=0.f;
    __syncthreads();

    // ---- Y = node@W12 + b12 -> split fp16 (hi+lo); exact fp32 colsums of consumed Y ----
    {
        int k = tid&63, n0 = (tid>>6)*32;
        float w12v[5];
        #pragma unroll
        for (int m=0;m<5;++m) w12v[m] = W12s[m*64+k];
        float bv = W12s[320+k];
        float sy = 0.f;
        for (int g=0; g<8; ++g){
            int n = n0 + g*4;
            f32x4 x0 = *(const f32x4*)&nodeT[n];
            f32x4 x1 = *(const f32x4*)&nodeT[128+n];
            f32x4 x2 = *(const f32x4*)&nodeT[256+n];
            f32x4 x3 = *(const f32x4*)&nodeT[384+n];
            f32x4 x4 = *(const f32x4*)&nodeT[512+n];
            f16x4 ph, pl;
            #pragma unroll
            for (int r=0;r<4;++r){
                float y = bv + x0[r]*w12v[0] + x1[r]*w12v[1] + x2[r]*w12v[2]
                             + x3[r]*w12v[3] + x4[r]*w12v[4];
                f16 yh = (f16)y;
                f16 yl = (f16)(y - (float)yh);
                ph[r]=yh; pl[r]=yl;
                sy += (float)yh + (float)yl;
            }
            *(f16x4*)&Yhi[k*S128+n] = ph;
            *(f16x4*)&Ylo[k*S128+n] = pl;
        }
        atomicAdd(&sumY[k], sy);
    }
    __syncthreads();

    // ---- M1: Z = Ac@(Yhi+Ylo) + 2*sumY + Y + b2 ----
    f32x4 accZ[2][4];
    #pragma unroll
    for (int p=0;p<2;++p){
        const int rbp = (2*w+p)*16 + l4*4;
        const int irp = (2*w+p)*16 + l15;
        #pragma unroll
        for (int ct=0;ct<4;++ct){
            int k = ct*16+l15;
            float base = 2.0f*sumY[k] + b2[k];
            f16x4 yh = *(const f16x4*)&Yhi[k*S128 + rbp];
            f16x4 yl = *(const f16x4*)&Ylo[k*S128 + rbp];
            #pragma unroll
            for (int r=0;r<4;++r) accZ[p][ct][r] = base + (float)yh[r] + (float)yl[r];
        }
        #pragma unroll
        for (int kk=0;kk<4;++kk){
            int ko = kk*32 + l4*8;
            f16x8 af = *(const f16x8*)&Alds[irp*S128 + ko];
            #pragma unroll
            for (int ct=0;ct<4;++ct){
                f16x8 bh = *(const f16x8*)&Yhi[(ct*16+l15)*S128 + ko];
                accZ[p][ct] = MFMA16(af, bh, accZ[p][ct]);
                f16x8 bl = *(const f16x8*)&Ylo[(ct*16+l15)*S128 + ko];
                accZ[p][ct] = MFMA16(af, bl, accZ[p][ct]);
            }
        }
        #pragma unroll
        for (int ct=0;ct<4;++ct){   // column sums -> mean c
            float v = accZ[p][ct][0]+accZ[p][ct][1]+accZ[p][ct][2]+accZ[p][ct][3];
            v += __shfl_xor(v,16,64); v += __shfl_xor(v,32,64);
            if (lane<16) atomicAdd(&c_ac[ct*16+lane], v);
        }
    }
    __syncthreads();
    if (tid<64) c_ac[tid] *= (1.0f/128.0f);
    __syncthreads();

    // ---- d2 = Z - c (split fp16, B-layout [n2][j]); cw/ctw = c@Ws/Wt fp32 ----
    #pragma unroll
    for (int p=0;p<2;++p){
        const int rbp = (2*w+p)*16 + l4*4;
        #pragma unroll
        for (int ct=0;ct<4;++ct){
            int n2 = ct*16+l15; float cv = c_ac[n2];
            f16x4 ph, pl;
            #pragma unroll
            for (int r=0;r<4;++r){
                float d = accZ[p][ct][r]-cv;
                f16 dh = (f16)d;
                ph[r]=dh; pl[r]=(f16)(d-(float)dh);
            }
            *(f16x4*)&d2hi[n2*S128 + rbp] = ph;
            *(f16x4*)&d2lo[n2*S128 + rbp] = pl;
        }
    }
    {
        int aux = tid&127;
        const float* Wx = (tid<128)? Ws : Wt;
        float s=0.f;
        for (int n2=0;n2<64;++n2) s += c_ac[n2]*Wx[n2*128+aux];
        ((tid<128)? cw : ctw)[aux] = s;
    }
    __syncthreads();

    // ---- M2: acc3 = Ac@(d2hi+d2lo) + d2 ----
    f32x4 acc3[2][4];
    #pragma unroll
    for (int p=0;p<2;++p){
        const int rbp = (2*w+p)*16 + l4*4;
        const int irp = (2*w+p)*16 + l15;
        #pragma unroll
        for (int ct=0;ct<4;++ct){
            int n2 = ct*16+l15;
            f16x4 dh = *(const f16x4*)&d2hi[n2*S128 + rbp];
            f16x4 dl = *(const f16x4*)&d2lo[n2*S128 + rbp];
            #pragma unroll
            for (int r=0;r<4;++r) acc3[p][ct][r] = (float)dh[r] + (float)dl[r];
        }
        #pragma unroll
        for (int kk=0;kk<4;++kk){
            int ko = kk*32 + l4*8;
            f16x8 af = *(const f16x8*)&Alds[irp*S128 + ko];
            #pragma unroll
            for (int ct=0;ct<4;++ct){
                f16x8 bh = *(const f16x8*)&d2hi[(ct*16+l15)*S128 + ko];
                acc3[p][ct] = MFMA16(af, bh, acc3[p][ct]);
                f16x8 bl = *(const f16x8*)&d2lo[(ct*16+l15)*S128 + ko];
                acc3[p][ct] = MFMA16(af, bl, acc3[p][ct]);
            }
        }
    }
    __syncthreads();   // Alds + d2 dead

    // ---- resid (overlays Alds) + stage WsB/WtB/Wsnd/Wtnd ----
    #pragma unroll
    for (int p=0;p<2;++p){
        const int rbp = (2*w+p)*16 + l4*4;
        #pragma unroll
        for (int ct=0;ct<4;++ct){
            int n2 = ct*16+l15;
            #pragma unroll
            for (int r=0;r<4;++r) resid[(rbp+r)*S72 + n2] = (f16)acc3[p][ct][r];
        }
    }
    for (int idx=tid; idx<8192; idx+=256){
        int n2 = idx>>7, aux = idx&127;
        WsB[aux*S68+n2] = (f16)Ws[idx];
        WtB[aux*S68+n2] = (f16)Wt[idx];
    }
    for (int i=tid;i<640;i+=256){
        Wsnd[i] = Ws[8192+i];
        Wtnd[i] = Wt[8192+i];
    }
    __syncthreads();

    // ---- G4: S/T = resid@Ws/Wt + (rs+1)*cw/ctw + node-part + bias; gated sum ----
    #pragma unroll
    for (int p=0;p<2;++p){
        const int rbp = (2*w+p)*16 + l4*4;
        const int irp = (2*w+p)*16 + l15;
        float nodev[4][5]; float rs1[4];
        #pragma unroll
        for (int r=0;r<4;++r){
            rs1[r] = rsL[rbp+r] + 1.0f;
            #pragma unroll
            for (int m=0;m<5;++m) nodev[r][m] = node_l[(rbp+r)*5+m];
        }
        #pragma unroll
        for (int cth=0; cth<2; ++cth){
            f32x4 aS[4], aT[4];
            #pragma unroll
            for (int ct=0;ct<4;++ct){
                int aux = (cth*4+ct)*16+l15;
                float cwv = cw[aux], ctv = ctw[aux];
                float bsv = bs[aux], btv = bt[aux];
                #pragma unroll
                for (int r=0;r<4;++r){
                    float ns=0.f, nt=0.f;
                    #pragma unroll
                    for (int m=0;m<5;++m){
                        float nv = nodev[r][m];
                        ns += nv*Wsnd[m*128+aux];
                        nt += nv*Wtnd[m*128+aux];
                    }
                    aS[ct][r] = bsv + rs1[r]*cwv + ns;
                    aT[ct][r] = btv + rs1[r]*ctv + nt;
                }
            }
            #pragma unroll
            for (int kk=0;kk<2;++kk){
                int ko = kk*32 + l4*8;
                f16x8 af = *(const f16x8*)&resid[irp*S72 + ko];
                #pragma unroll
                for (int ct=0;ct<4;++ct){
                    f16x8 bsf = *(const f16x8*)&WsB[((cth*4+ct)*16+l15)*S68 + ko];
                    aS[ct] = MFMA16(af, bsf, aS[ct]);
                    f16x8 btf = *(const f16x8*)&WtB[((cth*4+ct)*16+l15)*S68 + ko];
                    aT[ct] = MFMA16(af, btf, aT[ct]);
                }
            }
            #pragma unroll
            for (int ct=0;ct<4;++ct){
                float v = 0.f;
                #pragma unroll
                for (int r=0;r<4;++r) v += sigm(aS[ct][r])*tanhf_(aT[ct][r]);
                v += __shfl_xor(v,16,64); v += __shfl_xor(v,32,64);
                if (lane<16) atomicAdd(&g_ac[(cth*4+ct)*16+lane], v);
            }
        }
    }
    __syncthreads();

    // ---- head (t1l/t2l overlay node_l) ----
    if (tid<128) g_ac[tid] = tanhf_(g_ac[tid]);
    __syncthreads();
    if (tid<128){
        float s = bl1[tid];
        for (int a2=0;a2<128;++a2) s += g_ac[a2]*Wl1[a2*128+tid];
        t1l[tid] = s;
    }
    __syncthreads();
    if (tid<64){
        float s = bl2[tid];
        for (int o=0;o<128;++o) s += t1l[o]*Wl2[o*64+tid];
        t2l[tid] = s;
        out[512 + bidx*64 + tid] = s;   // output 1: g [B,64]
    }
    __syncthreads();
    if (w==0){
        float v = t2l[lane]*Wo[lane];
        v += __shfl_xor(v,1,64);  v += __shfl_xor(v,2,64);
        v += __shfl_xor(v,4,64);  v += __shfl_xor(v,8,64);
        v += __shfl_xor(v,16,64); v += __shfl_xor(v,32,64);
        if (lane==0) out[bidx] = v + bo[0];   // output 0: out [B,1]
    }
}

extern "C" void kernel_launch(void* const* d_in, const int* in_sizes, int n_in,
                              void* d_out, int out_size, void* d_ws, size_t ws_size,
                              hipStream_t stream) {
    (void)in_sizes; (void)n_in; (void)out_size; (void)d_ws; (void)ws_size;
    const float* adj  = (const float*)d_in[0];
    const float* node = (const float*)d_in[1];
    const float* W1   = (const float*)d_in[2];
    const float* b1   = (const float*)d_in[3];
    const float* W2   = (const float*)d_in[4];
    const float* b2   = (const float*)d_in[5];
    const float* Ws   = (const float*)d_in[6];
    const float* bs   = (const float*)d_in[7];
    const float* Wt   = (const float*)d_in[8];
    const float* bt   = (const float*)d_in[9];
    const float* Wl1  = (const float*)d_in[10];
    const float* bl1  = (const float*)d_in[11];
    const float* Wl2  = (const float*)d_in[12];
    const float* bl2  = (const float*)d_in[13];
    const float* Wo   = (const float*)d_in[14];
    const float* bo   = (const float*)d_in[15];

    k_main<<<dim3(512), dim3(256), 0, stream>>>(adj, node, W1,b1,W2,b2,Ws,bs,Wt,bt,
                                                Wl1,bl1,Wl2,bl2,Wo,bo, (float*)d_out);
}

// Round 6
// 70.822 us; speedup vs baseline: 1.4153x; 1.0613x over previous
//
#include <hip/hip_runtime.h>

typedef _Float16 f16;
typedef _Float16 f16x8 __attribute__((ext_vector_type(8)));
typedef _Float16 f16x4 __attribute__((ext_vector_type(4)));
typedef float f32x4 __attribute__((ext_vector_type(4)));

#define MFMA16(a,b,c) __builtin_amdgcn_mfma_f32_16x16x32_f16((a),(b),(c),0,0,0)

__device__ __forceinline__ float sigm(float x){ return 1.0f/(1.0f+__expf(-x)); }
__device__ __forceinline__ float tanhf_(float x){ return 1.0f - 2.0f/(1.0f+__expf(2.0f*x)); }

#define S136 136
#define S68  68
#define S72  72

// One block (256 thr, 4 waves) per batch element; 2 blocks/CU (LDS 81408).
// Register-streamed adj (plain float4 loads, no LDS staging round-trip),
// M1 (Z = Ac@Y) pipelined INTO the stream (one 16-row tile per 2 chunks,
// ct split across waves). Splits: Ac=A-2 fp16; Y,d2 hi+lo fp16 pairs;
// rank-1/mean parts exact fp32 (sumY, c, rowsum(A), c@Ws).
//
// LDS map (bytes):
// 0     Alds[128][136]f16 34816 | nodeT[640]f32 transient pre-stream | resid[128][72] after M2
// 34816 Yhi[64][136] -> d2hi -> WsB[128][68]
// 52224 Ylo[64][136] -> d2lo -> WtB[128][68]
// 69632 node_l[640] (t1l/t2l overlay at head) | 72192 W12s[384]
// 73728 Wsnd[640] | 76288 Wtnd[640] | 78848 sumY[64] | 79104 rsL[128]
// 79616 c_ac[64] | 79872 cw[128] | 80384 ctw[128] | 80896 g_ac[128] -> 81408

__global__ __launch_bounds__(256,2) void k_main(
    const float* __restrict__ adj,  const float* __restrict__ node_g,
    const float* __restrict__ W1,  const float* __restrict__ b1,
    const float* __restrict__ W2,  const float* __restrict__ b2,
    const float* __restrict__ Ws,  const float* __restrict__ bs,
    const float* __restrict__ Wt,  const float* __restrict__ bt,
    const float* __restrict__ Wl1, const float* __restrict__ bl1,
    const float* __restrict__ Wl2, const float* __restrict__ bl2,
    const float* __restrict__ Wo,  const float* __restrict__ bo,
    float* __restrict__ out)
{
    __shared__ __align__(16) char smem[81408];
    f16*   Alds  = (f16*)(smem);
    float* nodeT = (float*)(smem);
    f16*   resid = (f16*)(smem);
    f16*   Yhi   = (f16*)(smem+34816);
    f16*   d2hi  = (f16*)(smem+34816);
    f16*   WsB   = (f16*)(smem+34816);
    f16*   Ylo   = (f16*)(smem+52224);
    f16*   d2lo  = (f16*)(smem+52224);
    f16*   WtB   = (f16*)(smem+52224);
    float* node_l= (float*)(smem+69632);
    float* t1l   = (float*)(smem+69632);
    float* t2l   = (float*)(smem+70144);
    float* W12s  = (float*)(smem+72192);
    float* Wsnd  = (float*)(smem+73728);
    float* Wtnd  = (float*)(smem+76288);
    float* sumY  = (float*)(smem+78848);
    float* rsL   = (float*)(smem+79104);
    float* c_ac  = (float*)(smem+79616);
    float* cw    = (float*)(smem+79872);
    float* ctw   = (float*)(smem+80384);
    float* g_ac  = (float*)(smem+80896);

    const int bidx = blockIdx.x;
    const int tid  = threadIdx.x;
    const int w    = tid>>6, lane = tid&63;
    const int l15  = lane&15, l4 = lane>>4;

    // ---- phase 0: zeros + small staging + W12 = [W1;b1]@W2 (fp32) ----
    if (tid<64)  sumY[tid]=0.f;
    if (tid<128) g_ac[tid]=0.f;
    for (int i=tid;i<640;i+=256){
        node_l[i] = node_g[bidx*640+i];
        Wsnd[i]   = Ws[8192+i];
        Wtnd[i]   = Wt[8192+i];
    }
    for (int idx=tid; idx<384; idx+=256){
        int m = idx>>6, k = idx&63;
        float s = 0.f;
        if (m<5){ for (int c=0;c<128;++c) s += W1[m*128+c]*W2[c*64+k]; }
        else    { for (int c=0;c<128;++c) s += b1[c]*W2[c*64+k]; }
        W12s[idx] = s;
    }
    __syncthreads();
    for (int i=tid;i<640;i+=256){ int n=i/5, m=i-5*n; nodeT[m*128+n]=node_l[i]; }
    __syncthreads();

    // ---- Y = node@W12 + b12 -> split fp16 (hi+lo); exact fp32 colsums ----
    {
        int k = tid&63, n0 = (tid>>6)*32;
        float w12v[5];
        #pragma unroll
        for (int m=0;m<5;++m) w12v[m] = W12s[m*64+k];
        float bv = W12s[320+k];
        float sy = 0.f;
        #pragma unroll
        for (int g=0; g<8; ++g){
            int n = n0 + g*4;
            f32x4 x0 = *(const f32x4*)&nodeT[n];
            f32x4 x1 = *(const f32x4*)&nodeT[128+n];
            f32x4 x2 = *(const f32x4*)&nodeT[256+n];
            f32x4 x3 = *(const f32x4*)&nodeT[384+n];
            f32x4 x4 = *(const f32x4*)&nodeT[512+n];
            f16x4 ph, pl;
            #pragma unroll
            for (int r=0;r<4;++r){
                float y = bv + x0[r]*w12v[0] + x1[r]*w12v[1] + x2[r]*w12v[2]
                             + x3[r]*w12v[3] + x4[r]*w12v[4];
                f16 yh = (f16)y;
                f16 yl = (f16)(y - (float)yh);
                ph[r]=yh; pl[r]=yl;
                sy += (float)yh + (float)yl;
            }
            *(f16x4*)&Yhi[k*S136+n] = ph;
            *(f16x4*)&Ylo[k*S136+n] = pl;
        }
        atomicAdd(&sumY[k], sy);
    }
    __syncthreads();   // nodeT dead; Alds region free

    // ---- stream adj (register path) with M1 pipelined in ----
    const int   kcol  = w*16 + l15;                  // this wave's Z-column
    const float baseZ = 2.0f*sumY[kcol] + b2[kcol];
    const float4* asrc = (const float4*)(adj + (long long)bidx*81920);
    float4 cur[5];
    {
        const float4* p = asrc + 5*tid;
        #pragma unroll
        for (int k=0;k<5;++k) cur[k]=p[k];
    }
    f32x4 accZ[8];
    #pragma unroll
    for (int c=0;c<16;++c){
        float4 nxt[5];
        if (c<15){
            const float4* p = asrc + (c+1)*1280 + 5*tid;
            #pragma unroll
            for (int k=0;k<5;++k) nxt[k]=p[k];
        }
        float s0 = cur[0].y+cur[0].z+cur[0].w+cur[1].x;
        float s1 = cur[1].z+cur[1].w+cur[2].x+cur[2].y;
        float s2 = cur[2].w+cur[3].x+cur[3].y+cur[3].z;
        float s3 = cur[4].x+cur[4].y+cur[4].z+cur[4].w;
        {
            int r = c*8 + (tid>>5), j0 = (tid&31)*4;
            f16x4 o; o[0]=(f16)(s0-2.0f); o[1]=(f16)(s1-2.0f);
                     o[2]=(f16)(s2-2.0f); o[3]=(f16)(s3-2.0f);
            *(f16x4*)&Alds[r*S136 + j0] = o;
            float v = s0+s1+s2+s3;                 // exact fp32 rowsum
            v += __shfl_xor(v, 1, 64); v += __shfl_xor(v, 2, 64);
            v += __shfl_xor(v, 4, 64); v += __shfl_xor(v, 8, 64);
            v += __shfl_xor(v,16, 64);
            if ((tid&31)==0) rsL[r] = v;
        }
        asm volatile("s_waitcnt lgkmcnt(0)" ::: "memory");
        __builtin_amdgcn_s_barrier();              // raw: nxt loads stay in flight
        __builtin_amdgcn_sched_barrier(0);
        if (c&1){                                  // M1 on the finished 16-row tile
            const int t_ = c>>1;                   // compile-time (full unroll)
            {
                f16x4 yh = *(const f16x4*)&Yhi[kcol*S136 + t_*16 + l4*4];
                f16x4 yl = *(const f16x4*)&Ylo[kcol*S136 + t_*16 + l4*4];
                #pragma unroll
                for (int r=0;r<4;++r) accZ[t_][r] = baseZ + (float)yh[r] + (float)yl[r];
            }
            #pragma unroll
            for (int kk=0;kk<4;++kk){
                int ko = kk*32 + l4*8;
                f16x8 af = *(const f16x8*)&Alds[(t_*16+l15)*S136 + ko];
                f16x8 bh = *(const f16x8*)&Yhi[kcol*S136 + ko];
                accZ[t_] = MFMA16(af, bh, accZ[t_]);
                f16x8 bl = *(const f16x8*)&Ylo[kcol*S136 + ko];
                accZ[t_] = MFMA16(af, bl, accZ[t_]);
            }
        }
        if (c<15){
            #pragma unroll
            for (int k=0;k<5;++k) cur[k]=nxt[k];
        }
    }

    // ---- column means of Z (atomic-free: wave w owns cols w*16..w*16+15) ----
    {
        float cs = 0.f;
        #pragma unroll
        for (int t=0;t<8;++t) cs += accZ[t][0]+accZ[t][1]+accZ[t][2]+accZ[t][3];
        cs += __shfl_xor(cs,16,64); cs += __shfl_xor(cs,32,64);
        if (lane<16) c_ac[w*16+lane] = cs*(1.0f/128.0f);
    }
    __syncthreads();

    // ---- d2 = Z - c (split fp16, [n2][j]); cw/ctw = c@Ws/Wt fp32 ----
    {
        float cv = c_ac[kcol];
        #pragma unroll
        for (int t=0;t<8;++t){
            f16x4 ph, pl;
            #pragma unroll
            for (int r=0;r<4;++r){
                float d = accZ[t][r]-cv;
                f16 dh = (f16)d;
                ph[r]=dh; pl[r]=(f16)(d-(float)dh);
            }
            *(f16x4*)&d2hi[kcol*S136 + t*16 + l4*4] = ph;
            *(f16x4*)&d2lo[kcol*S136 + t*16 + l4*4] = pl;
        }
    }
    {
        int aux = tid&127;
        const float* Wx = (tid<128)? Ws : Wt;
        float s=0.f;
        for (int n2=0;n2<64;++n2) s += c_ac[n2]*Wx[n2*128+aux];
        ((tid<128)? cw : ctw)[aux] = s;
    }
    __syncthreads();

    // ---- M2: acc3 = Ac@(d2hi+d2lo) + d2 ----
    f32x4 acc3[2][4];
    #pragma unroll
    for (int p=0;p<2;++p){
        const int rbp = (2*w+p)*16 + l4*4;
        const int irp = (2*w+p)*16 + l15;
        #pragma unroll
        for (int ct=0;ct<4;++ct){
            int n2 = ct*16+l15;
            f16x4 dh = *(const f16x4*)&d2hi[n2*S136 + rbp];
            f16x4 dl = *(const f16x4*)&d2lo[n2*S136 + rbp];
            #pragma unroll
            for (int r=0;r<4;++r) acc3[p][ct][r] = (float)dh[r] + (float)dl[r];
        }
        #pragma unroll
        for (int kk=0;kk<4;++kk){
            int ko = kk*32 + l4*8;
            f16x8 af = *(const f16x8*)&Alds[irp*S136 + ko];
            #pragma unroll
            for (int ct=0;ct<4;++ct){
                f16x8 bh = *(const f16x8*)&d2hi[(ct*16+l15)*S136 + ko];
                acc3[p][ct] = MFMA16(af, bh, acc3[p][ct]);
                f16x8 bl = *(const f16x8*)&d2lo[(ct*16+l15)*S136 + ko];
                acc3[p][ct] = MFMA16(af, bl, acc3[p][ct]);
            }
        }
    }
    __syncthreads();   // Alds + d2 dead

    // ---- resid (overlays Alds) + vectorized WsB/WtB staging ----
    #pragma unroll
    for (int p=0;p<2;++p){
        const int rbp = (2*w+p)*16 + l4*4;
        #pragma unroll
        for (int ct=0;ct<4;++ct){
            int n2 = ct*16+l15;
            #pragma unroll
            for (int r=0;r<4;++r) resid[(rbp+r)*S72 + n2] = (f16)acc3[p][ct][r];
        }
    }
    {
        int aux = tid&127, half = tid>>7;
        f16x8 aS_[4], aT_[4];
        #pragma unroll
        for (int i=0;i<32;++i){
            int n2 = half*32+i;
            aS_[i>>3][i&7] = (f16)Ws[n2*128+aux];
            aT_[i>>3][i&7] = (f16)Wt[n2*128+aux];
        }
        #pragma unroll
        for (int q=0;q<4;++q){
            *(f16x8*)&WsB[aux*S68 + half*32 + q*8] = aS_[q];
            *(f16x8*)&WtB[aux*S68 + half*32 + q*8] = aT_[q];
        }
    }
    __syncthreads();

    // ---- G4: S/T = resid@Ws/Wt + (rs+1)*cw/ctw + node-part + bias; gated sum ----
    #pragma unroll
    for (int p=0;p<2;++p){
        const int rbp = (2*w+p)*16 + l4*4;
        const int irp = (2*w+p)*16 + l15;
        float nodev[4][5]; float rs1[4];
        #pragma unroll
        for (int r=0;r<4;++r){
            rs1[r] = rsL[rbp+r] + 1.0f;
            #pragma unroll
            for (int m=0;m<5;++m) nodev[r][m] = node_l[(rbp+r)*5+m];
        }
        #pragma unroll
        for (int cth=0; cth<2; ++cth){
            f32x4 aS[4], aT[4];
            #pragma unroll
            for (int ct=0;ct<4;++ct){
                int aux = (cth*4+ct)*16+l15;
                float cwv = cw[aux], ctv = ctw[aux];
                float bsv = bs[aux], btv = bt[aux];
                #pragma unroll
                for (int r=0;r<4;++r){
                    float ns=0.f, nt=0.f;
                    #pragma unroll
                    for (int m=0;m<5;++m){
                        float nv = nodev[r][m];
                        ns += nv*Wsnd[m*128+aux];
                        nt += nv*Wtnd[m*128+aux];
                    }
                    aS[ct][r] = bsv + rs1[r]*cwv + ns;
                    aT[ct][r] = btv + rs1[r]*ctv + nt;
                }
            }
            #pragma unroll
            for (int kk=0;kk<2;++kk){
                int ko = kk*32 + l4*8;
                f16x8 af = *(const f16x8*)&resid[irp*S72 + ko];
                #pragma unroll
                for (int ct=0;ct<4;++ct){
                    f16x8 bsf = *(const f16x8*)&WsB[((cth*4+ct)*16+l15)*S68 + ko];
                    aS[ct] = MFMA16(af, bsf, aS[ct]);
                    f16x8 btf = *(const f16x8*)&WtB[((cth*4+ct)*16+l15)*S68 + ko];
                    aT[ct] = MFMA16(af, btf, aT[ct]);
                }
            }
            #pragma unroll
            for (int ct=0;ct<4;++ct){
                float v = 0.f;
                #pragma unroll
                for (int r=0;r<4;++r) v += sigm(aS[ct][r])*tanhf_(aT[ct][r]);
                v += __shfl_xor(v,16,64); v += __shfl_xor(v,32,64);
                if (lane<16) atomicAdd(&g_ac[(cth*4+ct)*16+lane], v);
            }
        }
    }
    __syncthreads();

    // ---- head (parallelized dots; t1l/t2l overlay node_l) ----
    if (tid<128) g_ac[tid] = tanhf_(g_ac[tid]);
    __syncthreads();
    {
        int o = tid>>1, h = tid&1;
        float s = (h==0)? bl1[o] : 0.f;
        for (int a2=h*64; a2<h*64+64; ++a2) s += g_ac[a2]*Wl1[a2*128+o];
        s += __shfl_xor(s,1,64);
        if (h==0) t1l[o] = s;
    }
    __syncthreads();
    {
        int o = tid>>2, q = tid&3;
        float s = (q==0)? bl2[o] : 0.f;
        for (int k=q*32; k<q*32+32; ++k) s += t1l[k]*Wl2[k*64+o];
        s += __shfl_xor(s,1,64); s += __shfl_xor(s,2,64);
        if (q==0){ t2l[o] = s; out[512 + bidx*64 + o] = s; }   // output 1: g [B,64]
    }
    __syncthreads();
    if (w==0){
        float v = t2l[lane]*Wo[lane];
        v += __shfl_xor(v,1,64);  v += __shfl_xor(v,2,64);
        v += __shfl_xor(v,4,64);  v += __shfl_xor(v,8,64);
        v += __shfl_xor(v,16,64); v += __shfl_xor(v,32,64);
        if (lane==0) out[bidx] = v + bo[0];                    // output 0: out [B,1]
    }
}

extern "C" void kernel_launch(void* const* d_in, const int* in_sizes, int n_in,
                              void* d_out, int out_size, void* d_ws, size_t ws_size,
                              hipStream_t stream) {
    (void)in_sizes; (void)n_in; (void)out_size; (void)d_ws; (void)ws_size;
    const float* adj  = (const float*)d_in[0];
    const float* node = (const float*)d_in[1];
    const float* W1   = (const float*)d_in[2];
    const float* b1   = (const float*)d_in[3];
    const float* W2   = (const float*)d_in[4];
    const float* b2   = (const float*)d_in[5];
    const float* Ws   = (const float*)d_in[6];
    const float* bs   = (const float*)d_in[7];
    const float* Wt   = (const float*)d_in[8];
    const float* bt   = (const float*)d_in[9];
    const float* Wl1  = (const float*)d_in[10];
    const float* bl1  = (const float*)d_in[11];
    const float* Wl2  = (const float*)d_in[12];
    const float* bl2  = (const float*)d_in[13];
    const float* Wo   = (const float*)d_in[14];
    const float* bo   = (const float*)d_in[15];

    k_main<<<dim3(512), dim3(256), 0, stream>>>(adj, node, W1,b1,W2,b2,Ws,bs,Wt,bt,
                                                Wl1,bl1,Wl2,bl2,Wo,bo, (float*)d_out);
}